// Round 1
// baseline (361.922 us; speedup 1.0000x reference)
//
#include <hip/hip_runtime.h>

typedef unsigned short u16;
typedef unsigned int u32;
typedef __attribute__((ext_vector_type(8))) short short8;
typedef __attribute__((ext_vector_type(4))) float f32x4;

#define NATOMS 8000
#define MNBR 12
#define EPSV 1e-5f

// ---- ws layout (bytes) ----
#define PA_OFF 0                         // u16 PA[8000][768]
#define WTA_OFF 12288000                 // u16 WtAtom[768][64]
#define WTE_OFF 12386304                 // u16 WtEdge[512][64]
#define STATS_OFF 12451840               // f32 stats[1792]
#define PARAMS_OFF 12459008              // f32 params[768]
#define TBUF_OFF 12462080                // f32 tbuf[8000*64]
#define WS_NEED 14510080

// stats layout (f32 indices)
#define ST_BN1S 0
#define ST_BN1S2 128
#define ST_BNES 256
#define ST_BNES2 384
#define ST_A 512
#define ST_A2 640
#define ST_U2 768
#define ST_V2 896
#define ST_UB 1024
#define ST_VB 1152
#define ST_AU 1280
#define ST_AV 1408
#define ST_UV 1536
#define ST_BN2S 1664
#define ST_BN2S2 1728

// params layout: s1[0:128) t1[128:256) se[256:384) te[384:512) s3[512:640) t3[640:768)

__device__ __forceinline__ u16 f2bf(float f) {
  u32 u = __float_as_uint(f);
  u += 0x7FFFu + ((u >> 16) & 1u);
  return (u16)(u >> 16);
}
__device__ __forceinline__ float bf2f(u16 h) { return __uint_as_float(((u32)h) << 16); }

__device__ __forceinline__ float sigf(float x) {
  return __builtin_amdgcn_rcpf(1.f + __expf(-x));
}
__device__ __forceinline__ float spf(float x) {
  return fmaxf(x, 0.f) + __logf(1.f + __expf(-fabsf(x)));
}

__device__ __forceinline__ void mfma16(f32x4 &acc, short8 a, short8 b) {
  asm volatile("v_mfma_f32_16x16x32_bf16 %0, %1, %2, %0" : "+v"(acc) : "v"(a), "v"(b));
}
__device__ __forceinline__ void accfence(f32x4 &a) {
  asm volatile("s_nop 7\ns_nop 7\ns_nop 7" : "+v"(a));
}
__device__ __forceinline__ void initfence(f32x4 &a) {
  asm volatile("s_nop 1" : "+v"(a));
}

// stage 16 f32 -> 16 bf16 into XOR-swizzled LDS row (row stride 128B)
__device__ __forceinline__ void stage_row16(short* lds, int row, int c16, const float* __restrict__ src) {
  const float4* s4 = reinterpret_cast<const float4*>(src);
  float4 q0 = s4[0], q1 = s4[1], q2 = s4[2], q3 = s4[3];
  short8 lo, hi;
  lo[0]=(short)f2bf(q0.x); lo[1]=(short)f2bf(q0.y); lo[2]=(short)f2bf(q0.z); lo[3]=(short)f2bf(q0.w);
  lo[4]=(short)f2bf(q1.x); lo[5]=(short)f2bf(q1.y); lo[6]=(short)f2bf(q1.z); lo[7]=(short)f2bf(q1.w);
  hi[0]=(short)f2bf(q2.x); hi[1]=(short)f2bf(q2.y); hi[2]=(short)f2bf(q2.z); hi[3]=(short)f2bf(q2.w);
  hi[4]=(short)f2bf(q3.x); hi[5]=(short)f2bf(q3.y); hi[6]=(short)f2bf(q3.z); hi[7]=(short)f2bf(q3.w);
  int base = row * 128 + c16 * 2;
  int sw = (row & 7) << 4;
  *reinterpret_cast<short8*>(reinterpret_cast<char*>(lds) + (base ^ sw)) = lo;
  *reinterpret_cast<short8*>(reinterpret_cast<char*>(lds) + ((base + 16) ^ sw)) = hi;
}

__device__ __forceinline__ short8 lds_afrag(const short* lds, int row, int kbyte) {
  int off = (row * 128 + kbyte) ^ ((row & 7) << 4);
  return *reinterpret_cast<const short8*>(reinterpret_cast<const char*>(lds) + off);
}

// shared MFMA step for K2/K4: E-block (96 edges x 128 cols), wave w owns col-tiles {w, w+4}
__device__ __forceinline__ void mfma_block(const short* nbrT, const u16* __restrict__ WTE,
                                           int b, int w, int l, f32x4 (&acc)[6][2]) {
  short8 bfr[2][2];
#pragma unroll
  for (int p = 0; p < 2; ++p) {
    int wr = b * 128 + ((w + p * 4) << 4) + (l & 15);
#pragma unroll
    for (int kc = 0; kc < 2; ++kc)
      bfr[p][kc] = *reinterpret_cast<const short8*>(WTE + (size_t)wr * 64 + kc * 32 + ((l >> 4) << 3));
  }
#pragma unroll
  for (int rt = 0; rt < 6; ++rt)
#pragma unroll
    for (int p = 0; p < 2; ++p) { acc[rt][p] = f32x4{0.f, 0.f, 0.f, 0.f}; initfence(acc[rt][p]); }
#pragma unroll
  for (int rt = 0; rt < 6; ++rt) {
    int arow = rt * 16 + (l & 15);
    short8 a0 = lds_afrag(nbrT, arow, (l >> 4) << 4);
    short8 a1 = lds_afrag(nbrT, arow, 64 + ((l >> 4) << 4));
#pragma unroll
    for (int p = 0; p < 2; ++p) {
      mfma16(acc[rt][p], a0, bfr[p][0]);
      mfma16(acc[rt][p], a1, bfr[p][1]);
    }
  }
#pragma unroll
  for (int rt = 0; rt < 6; ++rt)
#pragma unroll
    for (int p = 0; p < 2; ++p) accfence(acc[rt][p]);
}

// ---------------- K0: transpose weights to bf16 [col][k] + zero stats ----------------
__global__ __launch_bounds__(256) void k0_prep(const float* __restrict__ W_full,
                                               const float* __restrict__ W_edge,
                                               const float* __restrict__ W_3body,
                                               u16* __restrict__ WTA, u16* __restrict__ WTE,
                                               float* __restrict__ stats) {
  int t = blockIdx.x * 256 + threadIdx.x;
  if (t < 1792) stats[t] = 0.f;
  if (t < 49152) {  // WtAtom: 768 cols x 64 k
    int col = t >> 6, k = t & 63;
    int blk = col >> 7, c = col & 127;
    float v;
    switch (blk) {
      case 0: v = W_full[k * 128 + c]; break;          // W1
      case 1: v = W_full[(64 + k) * 128 + c]; break;   // W2
      case 2: v = W_edge[k * 128 + c]; break;          // We1
      case 3: v = W_edge[(64 + k) * 128 + c]; break;   // We2
      case 4: v = W_3body[(64 + k) * 128 + c]; break;  // Wj
      default: v = W_3body[(128 + k) * 128 + c]; break;// Wl
    }
    WTA[t] = f2bf(v);
  } else if (t < 49152 + 32768) {  // WtEdge: 512 cols x 64 k
    int u = t - 49152;
    int col = u >> 6, k = u & 63;
    int blk = col >> 7, c = col & 127;
    float v;
    switch (blk) {
      case 0: v = W_full[(128 + k) * 128 + c]; break;   // W3
      case 1: v = W_edge[(128 + k) * 128 + c]; break;   // We3
      case 2: v = W_3body[(192 + k) * 128 + c]; break;  // Wij
      default: v = W_3body[(256 + k) * 128 + c]; break; // Wil
    }
    WTE[u] = f2bf(v);
  }
}

// ---------------- K1: PA = atom_in @ [W1|W2|We1|We2|Wj|Wl]  (bf16 table) ----------------
__global__ __launch_bounds__(256) void k1_pa(const float* __restrict__ atom_in,
                                             const u16* __restrict__ WTA,
                                             u16* __restrict__ PA) {
  __shared__ __align__(16) short xt[16 * 64];
  int t = threadIdx.x, l = t & 63, w = t >> 6;
  int ab = blockIdx.x * 16;
  if (t < 64) {
    int row = t >> 2, c16 = (t & 3) * 16;
    stage_row16(xt, row, c16, atom_in + (size_t)(ab + row) * 64 + c16);
  }
  __syncthreads();
  short8 a0 = lds_afrag(xt, l & 15, (l >> 4) << 4);
  short8 a1 = lds_afrag(xt, l & 15, 64 + ((l >> 4) << 4));
  for (int q = 0; q < 12; ++q) {
    int ct = w * 12 + q;
    int colg = ct * 16 + (l & 15);
    short8 b0 = *reinterpret_cast<const short8*>(WTA + (size_t)colg * 64 + ((l >> 4) << 3));
    short8 b1 = *reinterpret_cast<const short8*>(WTA + (size_t)colg * 64 + 32 + ((l >> 4) << 3));
    f32x4 acc = f32x4{0.f, 0.f, 0.f, 0.f};
    initfence(acc);
    mfma16(acc, a0, b0);
    mfma16(acc, a1, b1);
    accfence(acc);
#pragma unroll
    for (int r = 0; r < 4; ++r) {
      int row = ((l >> 4) << 2) + r;
      PA[(size_t)(ab + row) * 768 + colg] = f2bf(acc[r]);
    }
  }
}

// ---------------- K2: statistics pass ----------------
__global__ __launch_bounds__(256) void k2_stats(const float* __restrict__ atom_in,
                                                const float* __restrict__ nbr_fea,
                                                const int* __restrict__ nidx,
                                                const float* __restrict__ W_3body,
                                                const float* __restrict__ b_full,
                                                const float* __restrict__ b_edge,
                                                const float* __restrict__ b_3body,
                                                const u16* __restrict__ PA,
                                                const u16* __restrict__ WTE,
                                                float* __restrict__ stats) {
  __shared__ __align__(16) short nbrT[96 * 64];
  __shared__ int idx_s[96];
  __shared__ u16 paown[1024];
  __shared__ float ubar[1024], vbar[1024];
  __shared__ float xown[512];
  __shared__ float redscr[128 * 7];
  int t = threadIdx.x, l = t & 63, w = t >> 6;
  int ab = blockIdx.x * 8, eb = ab * 12;

  for (int u = t; u < 384; u += 256) {
    int row = u >> 2, c16 = (u & 3) * 16;
    stage_row16(nbrT, row, c16, nbr_fea + (size_t)(eb + row) * 64 + c16);
  }
  if (t < 96) idx_s[t] = nidx[eb + t];
  for (int i = t; i < 1024; i += 256) { ubar[i] = 0.f; vbar[i] = 0.f; }
  xown[t] = atom_in[ab * 64 + t];
  xown[t + 256] = atom_in[ab * 64 + 256 + t];

  for (int b = 0; b < 4; ++b) {
    __syncthreads();
    if (b < 2) {
      int ownOff = b ? 256 : 0;
      int i = t * 4, a = i >> 7, c = i & 127;
      *reinterpret_cast<uint2*>(&paown[i]) =
          *reinterpret_cast<const uint2*>(PA + (size_t)(ab + a) * 768 + ownOff + c);
    }
    f32x4 acc[6][2];
    mfma_block(nbrT, WTE, b, w, l, acc);
    __syncthreads();

    int nbrOff = (b == 0) ? 128 : (b == 1) ? 384 : (b == 2) ? 512 : 640;
    int col0 = (w << 4) + (l & 15), col1 = col0 + 64;
    float bias0 = 0.f, bias1 = 0.f;
    if (b < 2) { const float* bp = b ? b_edge : b_full; bias0 = bp[col0]; bias1 = bp[col1]; }
    float* uvb = (b == 2) ? ubar : vbar;
    float vs0 = 0.f, vs1 = 0.f, q0 = 0.f, q1 = 0.f;
#pragma unroll
    for (int rt = 0; rt < 6; ++rt) {
#pragma unroll
      for (int r = 0; r < 4; ++r) {
        int row = rt * 16 + ((l >> 4) << 2) + r;
        int a12 = row / 12;
        size_t pb = (size_t)idx_s[row] * 768 + nbrOff;
        float v0 = acc[rt][0][r] + bf2f(PA[pb + col0]);
        float v1 = acc[rt][1][r] + bf2f(PA[pb + col1]);
        if (b < 2) {
          v0 += bf2f(paown[a12 * 128 + col0]) + bias0;
          v1 += bf2f(paown[a12 * 128 + col1]) + bias1;
          vs0 += v0; q0 += v0 * v0; vs1 += v1; q1 += v1 * v1;
        } else {
          atomicAdd(&uvb[a12 * 128 + col0], v0);
          atomicAdd(&uvb[a12 * 128 + col1], v1);
          q0 += v0 * v0; q1 += v1 * v1;
        }
      }
    }
    vs0 += __shfl_xor(vs0, 16); vs0 += __shfl_xor(vs0, 32);
    vs1 += __shfl_xor(vs1, 16); vs1 += __shfl_xor(vs1, 32);
    q0 += __shfl_xor(q0, 16); q0 += __shfl_xor(q0, 32);
    q1 += __shfl_xor(q1, 16); q1 += __shfl_xor(q1, 32);
    if (l < 16) {
      if (b < 2) {
        int base = b ? ST_BNES : ST_BN1S;
        atomicAdd(&stats[base + col0], vs0);
        atomicAdd(&stats[base + 128 + col0], q0);
        atomicAdd(&stats[base + col1], vs1);
        atomicAdd(&stats[base + 128 + col1], q1);
      } else {
        int sb = (b == 2) ? ST_U2 : ST_V2;
        atomicAdd(&stats[sb + col0], q0);
        atomicAdd(&stats[sb + col1], q1);
      }
    }
  }
  __syncthreads();

  // analytic bn3 sums: a in f32 (x_i @ Wa + b3), ubar/vbar means
  {
    int c = t & 127, h = t >> 7;
    float dv[4] = {0.f, 0.f, 0.f, 0.f};
    for (int k = 0; k < 64; ++k) {
      float wk = W_3body[k * 128 + c];
#pragma unroll
      for (int a4 = 0; a4 < 4; ++a4) dv[a4] += xown[(h * 4 + a4) * 64 + k] * wk;
    }
    float b3v = b_3body[c];
    float pA = 0.f, pA2 = 0.f, pUb = 0.f, pVb = 0.f, pAU = 0.f, pAV = 0.f, pUV = 0.f;
#pragma unroll
    for (int a4 = 0; a4 < 4; ++a4) {
      int a = h * 4 + a4;
      float aval = dv[a4] + b3v;
      float ub = ubar[a * 128 + c] * (1.f / 12.f);
      float vb = vbar[a * 128 + c] * (1.f / 12.f);
      pA += aval; pA2 += aval * aval; pUb += ub; pVb += vb;
      pAU += aval * ub; pAV += aval * vb; pUV += ub * vb;
    }
    if (h == 1) {
      float* rs = &redscr[c * 7];
      rs[0] = pA; rs[1] = pA2; rs[2] = pUb; rs[3] = pVb; rs[4] = pAU; rs[5] = pAV; rs[6] = pUV;
    }
    __syncthreads();
    if (h == 0) {
      const float* rs = &redscr[c * 7];
      atomicAdd(&stats[ST_A + c], pA + rs[0]);
      atomicAdd(&stats[ST_A2 + c], pA2 + rs[1]);
      atomicAdd(&stats[ST_UB + c], pUb + rs[2]);
      atomicAdd(&stats[ST_VB + c], pVb + rs[3]);
      atomicAdd(&stats[ST_AU + c], pAU + rs[4]);
      atomicAdd(&stats[ST_AV + c], pAV + rs[5]);
      atomicAdd(&stats[ST_UV + c], pUV + rs[6]);
    }
  }
}

// ---------------- K3: finalize bn1/bne/bn3 affine params ----------------
__global__ void k3_params(const float* __restrict__ stats,
                          const float* __restrict__ g1, const float* __restrict__ be1,
                          const float* __restrict__ ge, const float* __restrict__ bee,
                          const float* __restrict__ g3, const float* __restrict__ be3,
                          float* __restrict__ params) {
  int c = threadIdx.x;
  if (c >= 128) return;
  const float cnt1 = 1.f / 96000.f;
  {
    float m = stats[ST_BN1S + c] * cnt1;
    float var = stats[ST_BN1S2 + c] * cnt1 - m * m;
    float s = g1[c] * rsqrtf(fmaxf(var, 0.f) + EPSV);
    params[c] = s; params[128 + c] = be1[c] - m * s;
  }
  {
    float m = stats[ST_BNES + c] * cnt1;
    float var = stats[ST_BNES2 + c] * cnt1 - m * m;
    float s = ge[c] * rsqrtf(fmaxf(var, 0.f) + EPSV);
    params[256 + c] = s; params[384 + c] = bee[c] - m * s;
  }
  {
    float Nf = (float)NATOMS;
    float A_ = stats[ST_A + c], A2 = stats[ST_A2 + c];
    float U2 = stats[ST_U2 + c], V2 = stats[ST_V2 + c];
    float Ub = stats[ST_UB + c], Vb = stats[ST_VB + c];
    float AU = stats[ST_AU + c], AV = stats[ST_AV + c], UV = stats[ST_UV + c];
    float m = (A_ + Ub + Vb) / Nf;
    float ez2 = A2 / Nf + (U2 + V2) / (Nf * 12.f) + 2.f * (AU + AV + UV) / Nf;
    float var = ez2 - m * m;
    float s = g3[c] * rsqrtf(fmaxf(var, 0.f) + EPSV);
    params[512 + c] = s; params[640 + c] = be3[c] - m * s;
  }
}

// ---------------- K4: main pass (gates, edge-out, 3-body, bn2 sums) ----------------
__global__ __launch_bounds__(256) void k4_main(const float* __restrict__ atom_in,
                                               const float* __restrict__ nbr_fea,
                                               const int* __restrict__ nidx,
                                               const float* __restrict__ W_3body,
                                               const float* __restrict__ b_full,
                                               const float* __restrict__ b_edge,
                                               const float* __restrict__ b_3body,
                                               const u16* __restrict__ PA,
                                               const u16* __restrict__ WTE,
                                               const float* __restrict__ params,
                                               float* __restrict__ tbuf,
                                               float* __restrict__ stats,
                                               float* __restrict__ out_nbr) {
  __shared__ __align__(16) short nbrT[96 * 64];
  __shared__ int idx_s[96];
  __shared__ u16 paown[1024];
  __shared__ u16 u_s[96 * 128], v_s[96 * 128];
  __shared__ float t2buf[512];
  __shared__ float params_s[768];
  __shared__ float bias_s[256];
  __shared__ float a_s[1024];
  __shared__ float xown[512];
  __shared__ float redscr2[512];
  int t = threadIdx.x, l = t & 63, w = t >> 6;
  int ab = blockIdx.x * 8, eb = ab * 12;

  for (int u = t; u < 384; u += 256) {
    int row = u >> 2, c16 = (u & 3) * 16;
    stage_row16(nbrT, row, c16, nbr_fea + (size_t)(eb + row) * 64 + c16);
  }
  if (t < 96) idx_s[t] = nidx[eb + t];
  xown[t] = atom_in[ab * 64 + t];
  xown[t + 256] = atom_in[ab * 64 + 256 + t];
  params_s[t] = params[t];
  params_s[t + 256] = params[t + 256];
  params_s[t + 512] = params[t + 512];
  if (t < 128) { bias_s[t] = b_full[t]; bias_s[128 + t] = b_edge[t]; }
  t2buf[t] = 0.f; t2buf[t + 256] = 0.f;
  __syncthreads();

  // a' = (x_i @ Wa + b3) * s3 + t3 in f32
  {
    int c = t & 127, h = t >> 7;
    float dv[4] = {0.f, 0.f, 0.f, 0.f};
    for (int k = 0; k < 64; ++k) {
      float wk = W_3body[k * 128 + c];
#pragma unroll
      for (int a4 = 0; a4 < 4; ++a4) dv[a4] += xown[(h * 4 + a4) * 64 + k] * wk;
    }
    float s3 = params_s[512 + c], t3 = params_s[640 + c];
    float b3v = b_3body[c];
#pragma unroll
    for (int a4 = 0; a4 < 4; ++a4) a_s[(h * 4 + a4) * 128 + c] = (dv[a4] + b3v) * s3 + t3;
  }

  for (int b = 0; b < 4; ++b) {
    __syncthreads();
    if (b < 2) {
      int ownOff = b ? 256 : 0;
      int i = t * 4, a = i >> 7, c = i & 127;
      *reinterpret_cast<uint2*>(&paown[i]) =
          *reinterpret_cast<const uint2*>(PA + (size_t)(ab + a) * 768 + ownOff + c);
    }
    f32x4 acc[6][2];
    mfma_block(nbrT, WTE, b, w, l, acc);
    __syncthreads();

    int col0 = (w << 4) + (l & 15), col1 = col0 + 64;
    if (b < 2) {
      int nbrOff = b ? 384 : 128;
      float bias0 = bias_s[b * 128 + col0], bias1 = bias_s[b * 128 + col1];
      float sc0 = params_s[b * 256 + col0], sh0 = params_s[b * 256 + 128 + col0];
      float sc1 = params_s[b * 256 + col1], sh1 = params_s[b * 256 + 128 + col1];
#pragma unroll
      for (int rt = 0; rt < 6; ++rt) {
#pragma unroll
        for (int r = 0; r < 4; ++r) {
          int row = rt * 16 + ((l >> 4) << 2) + r;
          int a12 = row / 12;
          size_t pb = (size_t)idx_s[row] * 768 + nbrOff;
          float v0 = acc[rt][0][r] + bf2f(PA[pb + col0]) + bf2f(paown[a12 * 128 + col0]) + bias0;
          float v1 = acc[rt][1][r] + bf2f(PA[pb + col1]) + bf2f(paown[a12 * 128 + col1]) + bias1;
          float gate = sigf(v0 * sc0 + sh0) * spf(v1 * sc1 + sh1);
          if (b == 0) {
            atomicAdd(&t2buf[a12 * 64 + col0], gate);
          } else {
            size_t eg = (size_t)(eb + row) * 64 + col0;
            out_nbr[eg] = nbr_fea[eg] + gate;
          }
        }
      }
    } else {
      int nbrOff = (b == 2) ? 512 : 640;
      u16* dst = (b == 2) ? u_s : v_s;
      float s30 = params_s[512 + col0], s31 = params_s[512 + col1];
#pragma unroll
      for (int rt = 0; rt < 6; ++rt) {
#pragma unroll
        for (int r = 0; r < 4; ++r) {
          int row = rt * 16 + ((l >> 4) << 2) + r;
          size_t pb = (size_t)idx_s[row] * 768 + nbrOff;
          float v0 = (acc[rt][0][r] + bf2f(PA[pb + col0])) * s30;
          float v1 = (acc[rt][1][r] + bf2f(PA[pb + col1])) * s31;
          dst[row * 128 + col0] = f2bf(v0);
          dst[row * 128 + col1] = f2bf(v1);
        }
      }
    }
  }
  __syncthreads();

  // 3-body: per (atom, channel-pair) loop over 144 (j,l) pairs, all in LDS/regs
  {
    int c = t & 63, s = t >> 6;
#pragma unroll
    for (int aa = 0; aa < 2; ++aa) {
      int a = 2 * s + aa;
      float af = a_s[a * 128 + c], ac = a_s[a * 128 + 64 + c];
      float vfl[12], vcl[12];
#pragma unroll
      for (int j2 = 0; j2 < 12; ++j2) {
        vfl[j2] = bf2f(v_s[(a * 12 + j2) * 128 + c]);
        vcl[j2] = bf2f(v_s[(a * 12 + j2) * 128 + 64 + c]);
      }
      float acc3 = 0.f;
      for (int j = 0; j < 12; ++j) {
        float tf = af + bf2f(u_s[(a * 12 + j) * 128 + c]);
        float tc = ac + bf2f(u_s[(a * 12 + j) * 128 + 64 + c]);
#pragma unroll
        for (int l2 = 0; l2 < 12; ++l2) acc3 += sigf(tf + vfl[l2]) * spf(tc + vcl[l2]);
      }
      t2buf[a * 64 + c] += acc3;
    }
  }
  __syncthreads();

  // write t = two_body + three_body; bn2 partial sums
  {
    int c = t & 63;
    float x0 = t2buf[t];
    float x1 = t2buf[t + 256];
    tbuf[(size_t)(ab + (t >> 6)) * 64 + c] = x0;
    tbuf[(size_t)(ab + (t >> 6) + 4) * 64 + c] = x1;
    redscr2[t] = x0 + x1;
    redscr2[256 + t] = x0 * x0 + x1 * x1;
    __syncthreads();
    if (t < 64) {
      float s = redscr2[t] + redscr2[t + 64] + redscr2[t + 128] + redscr2[t + 192];
      float s2 = redscr2[256 + t] + redscr2[256 + t + 64] + redscr2[256 + t + 128] + redscr2[256 + t + 192];
      atomicAdd(&stats[ST_BN2S + t], s);
      atomicAdd(&stats[ST_BN2S2 + t], s2);
    }
  }
}

// ---------------- K6: bn2 + final softplus ----------------
__global__ __launch_bounds__(256) void k6_out(const float* __restrict__ atom_in,
                                              const float* __restrict__ tbuf,
                                              const float* __restrict__ stats,
                                              const float* __restrict__ g2,
                                              const float* __restrict__ be2,
                                              float* __restrict__ out_atom) {
  __shared__ float sc[64], sh[64];
  int t = threadIdx.x;
  if (t < 64) {
    float S = stats[ST_BN2S + t], S2 = stats[ST_BN2S2 + t];
    float m = S * (1.f / (float)NATOMS);
    float var = S2 * (1.f / (float)NATOMS) - m * m;
    float s = g2[t] * rsqrtf(fmaxf(var, 0.f) + EPSV);
    sc[t] = s; sh[t] = be2[t] - m * s;
  }
  __syncthreads();
  int i = blockIdx.x * 256 + t;
  if (i < NATOMS * 64) {
    int c = i & 63;
    float v = atom_in[i] + tbuf[i] * sc[c] + sh[c];
    out_atom[i] = spf(v);
  }
}

extern "C" void kernel_launch(void* const* d_in, const int* in_sizes, int n_in,
                              void* d_out, int out_size, void* d_ws, size_t ws_size,
                              hipStream_t stream) {
  if (ws_size < (size_t)WS_NEED) return;
  const float* atom_in = (const float*)d_in[0];
  const float* nbr_fea = (const float*)d_in[1];
  const int* nidx = (const int*)d_in[2];
  const float* W_full = (const float*)d_in[3];
  const float* b_full = (const float*)d_in[4];
  const float* g1 = (const float*)d_in[5];
  const float* be1 = (const float*)d_in[6];
  const float* W_edge = (const float*)d_in[7];
  const float* b_edge = (const float*)d_in[8];
  const float* ge = (const float*)d_in[9];
  const float* bee = (const float*)d_in[10];
  const float* W_3body = (const float*)d_in[11];
  const float* b_3body = (const float*)d_in[12];
  const float* g3 = (const float*)d_in[13];
  const float* be3 = (const float*)d_in[14];
  const float* g2 = (const float*)d_in[15];
  const float* be2 = (const float*)d_in[16];

  char* ws = (char*)d_ws;
  u16* PA = (u16*)(ws + PA_OFF);
  u16* WTA = (u16*)(ws + WTA_OFF);
  u16* WTE = (u16*)(ws + WTE_OFF);
  float* stats = (float*)(ws + STATS_OFF);
  float* params = (float*)(ws + PARAMS_OFF);
  float* tbuf = (float*)(ws + TBUF_OFF);

  float* out_atom = (float*)d_out;
  float* out_nbr = out_atom + NATOMS * 64;

  k0_prep<<<320, 256, 0, stream>>>(W_full, W_edge, W_3body, WTA, WTE, stats);
  k1_pa<<<500, 256, 0, stream>>>(atom_in, WTA, PA);
  k2_stats<<<1000, 256, 0, stream>>>(atom_in, nbr_fea, nidx, W_3body, b_full, b_edge, b_3body,
                                     PA, WTE, stats);
  k3_params<<<1, 128, 0, stream>>>(stats, g1, be1, ge, bee, g3, be3, params);
  k4_main<<<1000, 256, 0, stream>>>(atom_in, nbr_fea, nidx, W_3body, b_full, b_edge, b_3body,
                                    PA, WTE, params, tbuf, stats, out_nbr);
  k6_out<<<2000, 256, 0, stream>>>(atom_in, tbuf, stats, g2, be2, out_atom);
}